// Round 1
// baseline (2015.911 us; speedup 1.0000x reference)
//
#include <hip/hip_runtime.h>
#include <stdint.h>

// LSTMPool: B=4096,T=128,F=E=TD=128 -> A=384, 4F=512
// K0: weight transpose/convert fp32->bf16, [n][k] k-contiguous (MFMA B-frag ready)
// K1: X = seq_x @ Wi + bh   (bf16 MFMA, LDS-free, X stored bf16 in ws)
// K2: LSTM recurrence       (bf16 MFMA for h@Wh, Wh frags register-cached)
// K3a/b: merge layer        (bf16 MFMA)
// T dimension chunked by Tc = 2^lTc chosen from ws_size (X buffer = 4 MB * Tc).

#define B_ 4096
#define T_ 128

typedef __attribute__((ext_vector_type(8))) short bf16x8;
typedef __attribute__((ext_vector_type(4))) float f32x4;

__device__ __forceinline__ unsigned short f2bf_rne(float f){
    unsigned u = __float_as_uint(f);
    u = u + 0x7FFFu + ((u >> 16) & 1u);
    return (unsigned short)(u >> 16);
}
__device__ __forceinline__ float bf2f(unsigned short s){
    return __uint_as_float(((unsigned)s) << 16);
}
// pack 2 floats -> 2 bf16 (round-half-up: +0x8000 then take high16) in one v_perm
__device__ __forceinline__ int pack_rnd2(float f0, float f1){
    unsigned a = __float_as_uint(f0) + 0x8000u;
    unsigned b = __float_as_uint(f1) + 0x8000u;
    return (int)__builtin_amdgcn_perm(b, a, 0x07060302u);
}
__device__ __forceinline__ bf16x8 pack8(float4 lo, float4 hi){
    union { int i[4]; bf16x8 v; } u;
    u.i[0] = pack_rnd2(lo.x, lo.y);
    u.i[1] = pack_rnd2(lo.z, lo.w);
    u.i[2] = pack_rnd2(hi.x, hi.y);
    u.i[3] = pack_rnd2(hi.z, hi.w);
    return u.v;
}
__device__ __forceinline__ float frcp(float x){ return __builtin_amdgcn_rcpf(x); }
__device__ __forceinline__ float fsig(float x){ return frcp(1.0f + __expf(-x)); }
__device__ __forceinline__ float ftanh(float x){ return 1.0f - 2.0f*frcp(1.0f + __expf(2.0f*x)); }

// ---------------- K0: weight prep ----------------
// WiT[512][384], WhT[512][128], W1T[128][256], W2T[128][128]  (all bf16, k contiguous)
__global__ void k0_prep(const float* __restrict__ Wi, const float* __restrict__ Wh,
                        const float* __restrict__ W1, const float* __restrict__ W2,
                        unsigned short* __restrict__ WiT, unsigned short* __restrict__ WhT,
                        unsigned short* __restrict__ W1T, unsigned short* __restrict__ W2T)
{
    int gid = blockIdx.x * 256 + threadIdx.x;
    if (gid < 196608){                       // Wi [384][512]
        int n = gid & 511, k = gid >> 9;
        WiT[n*384 + k] = f2bf_rne(Wi[gid]);
    } else if (gid < 262144){                // Wh [128][512]
        int i = gid - 196608;
        int n = i & 511, k = i >> 9;
        WhT[n*128 + k] = f2bf_rne(Wh[i]);
    } else if (gid < 294912){                // W1 [256][128]
        int i = gid - 262144;
        int n = i & 127, k = i >> 7;
        W1T[n*256 + k] = f2bf_rne(W1[i]);
    } else if (gid < 311296){                // W2 [128][128]
        int i = gid - 294912;
        int n = i & 127, k = i >> 7;
        W2T[n*128 + k] = f2bf_rne(W2[i]);
    }
}

// ---------------- K1: X = seq_x @ Wi + bh ----------------
// grid (4, 32*Tc), block 256 (4 waves). Wave tile 32m x 128n (2 mt x 8 nt).
// A frags: global fp32 -> packed bf16. B frags: global bf16 WiT (L2-resident).
__global__ __launch_bounds__(256, 2)
void k1_gemm_x(const float* __restrict__ seq, const float* __restrict__ seqe,
               const float* __restrict__ seqt, const float* __restrict__ bh,
               const unsigned short* __restrict__ WiT,
               unsigned short* __restrict__ X, int t0, int lTc)
{
    const int Tc = 1 << lTc;
    const int tid = threadIdx.x;
    const int w = tid >> 6, l = tid & 63;
    const int lane16 = l & 15, quad = l >> 4;
    const int m0 = blockIdx.y * 128 + w * 32;   // first row (mi space) of this wave
    const int n0 = blockIdx.x * 128;

    f32x4 acc[2][8];
    for (int nt = 0; nt < 8; ++nt){
        float b = bh[n0 + nt*16 + lane16];
        f32x4 v = {b, b, b, b};
        acc[0][nt] = v; acc[1][nt] = v;
    }
    long rowoff[2];
    for (int mt = 0; mt < 2; ++mt){
        int mi = m0 + mt*16 + lane16;
        long bt = (long)(mi >> lTc) * T_ + t0 + (mi & (Tc - 1));
        rowoff[mt] = bt * 128;
    }
#pragma unroll
    for (int kc = 0; kc < 12; ++kc){
        const int k0 = kc * 32;
        const float* src = (k0 < 128) ? seq : (k0 < 256 ? seqe : seqt);
        const int klane = (k0 & 127) + quad*8;
        bf16x8 af[2];
        for (int mt = 0; mt < 2; ++mt){
            const float* p = src + rowoff[mt] + klane;
            float4 lo = *reinterpret_cast<const float4*>(p);
            float4 hi = *reinterpret_cast<const float4*>(p + 4);
            af[mt] = pack8(lo, hi);
        }
        for (int nt = 0; nt < 8; ++nt){
            int n = n0 + nt*16 + lane16;
            bf16x8 bf = *reinterpret_cast<const bf16x8*>(WiT + (long)n*384 + k0 + quad*8);
            acc[0][nt] = __builtin_amdgcn_mfma_f32_16x16x32_bf16(af[0], bf, acc[0][nt], 0, 0, 0);
            acc[1][nt] = __builtin_amdgcn_mfma_f32_16x16x32_bf16(af[1], bf, acc[1][nt], 0, 0, 0);
        }
    }
    // store X bf16: C/D layout row = quad*4 + r, col = lane16
    for (int mt = 0; mt < 2; ++mt){
        for (int r = 0; r < 4; ++r){
            long mi = m0 + mt*16 + quad*4 + r;
            unsigned short* xp = X + mi*512 + n0 + lane16;
            for (int nt = 0; nt < 8; ++nt)
                xp[nt*16] = f2bf_rne(acc[mt][nt][r]);
        }
    }
}

// ---------------- K2: LSTM recurrence ----------------
// grid 256 blocks (16 rows each), block 512 = 8 waves, wave w owns cols j in [16w,16w+16).
// Wh B-frags (16 per wave) cached in registers across the whole T loop.
// h lives in LDS (bf16, [16][136] padded, double-buffered), 1 barrier/step.
__global__ __launch_bounds__(512, 2)
void k2_lstm(const unsigned short* __restrict__ X, const unsigned short* __restrict__ WhT,
             unsigned short* __restrict__ hn, float* __restrict__ c_state,
             int t0, int lTc)
{
    const int Tc = 1 << lTc;
    const int tid = threadIdx.x;
    const int w = tid >> 6, l = tid & 63;
    const int lane16 = l & 15, quad = l >> 4;
    const int b0 = blockIdx.x * 16;
    const int j = w*16 + lane16;            // cell column 0..127

    __shared__ __align__(16) unsigned short hlds[2][16*136];

    // register-cached Wh fragments: bfrag[g][k8]
    bf16x8 bfrag[4][4];
#pragma unroll
    for (int g = 0; g < 4; ++g)
#pragma unroll
        for (int k8 = 0; k8 < 4; ++k8)
            bfrag[g][k8] = *reinterpret_cast<const bf16x8*>(WhT + (long)(128*g + j)*128 + 32*k8 + quad*8);

    float c_reg[4];
    if (t0 == 0){
        for (int idx = tid; idx < 16*136; idx += 512) hlds[0][idx] = 0;
        for (int r = 0; r < 4; ++r) c_reg[r] = 0.0f;
    } else {
        for (int idx = tid; idx < 2048; idx += 512){
            int r = idx >> 7, k = idx & 127;
            hlds[0][r*136 + k] = hn[(long)(b0 + r)*128 + k];
        }
        for (int r = 0; r < 4; ++r)
            c_reg[r] = c_state[(long)(b0 + quad*4 + r)*128 + j];
    }
    __syncthreads();

    int p = 0;
    float h2[4] = {0.f, 0.f, 0.f, 0.f};
    for (int tt = 0; tt < Tc; ++tt){
        // X for this step (issued early; consumed after MFMAs)
        float xz[4][4];
#pragma unroll
        for (int g = 0; g < 4; ++g)
#pragma unroll
            for (int r = 0; r < 4; ++r){
                long mi = ((long)(b0 + quad*4 + r) << lTc) + tt;
                xz[g][r] = bf2f(X[mi*512 + 128*g + j]);
            }
        // A frags from LDS h
        bf16x8 af[4];
#pragma unroll
        for (int k8 = 0; k8 < 4; ++k8)
            af[k8] = *reinterpret_cast<const bf16x8*>(&hlds[p][lane16*136 + 32*k8 + quad*8]);
        // z_h = h @ Wh
        f32x4 acc[4];
#pragma unroll
        for (int g = 0; g < 4; ++g){
            f32x4 a = {0.f, 0.f, 0.f, 0.f};
#pragma unroll
            for (int k8 = 0; k8 < 4; ++k8)
                a = __builtin_amdgcn_mfma_f32_16x16x32_bf16(af[k8], bfrag[g][k8], a, 0, 0, 0);
            acc[g] = a;
        }
        // gates; cell (row = quad*4+r, col = j) is same lane/reg slot across all 4 g
#pragma unroll
        for (int r = 0; r < 4; ++r){
            float zi = xz[0][r] + acc[0][r];
            float zf = xz[1][r] + acc[1][r];
            float zg = xz[2][r] + acc[2][r];
            float zo = xz[3][r] + acc[3][r];
            float cc = fsig(zf)*c_reg[r] + fsig(zi)*ftanh(zg);
            c_reg[r] = cc;
            h2[r] = fsig(zo)*ftanh(cc);
        }
#pragma unroll
        for (int r = 0; r < 4; ++r)
            hlds[p ^ 1][(quad*4 + r)*136 + j] = f2bf_rne(h2[r]);
        __syncthreads();
        p ^= 1;
    }
    // chunk end: persist h (bf16, doubles as hn) and c
    for (int r = 0; r < 4; ++r){
        hn[(long)(b0 + quad*4 + r)*128 + j] = f2bf_rne(h2[r]);
        c_state[(long)(b0 + quad*4 + r)*128 + j] = c_reg[r];
    }
}

// ---------------- K3a: hid = relu([hn || src] @ W1 + b1) ----------------
// grid 64, block 256 (4 waves x 16 rows). N = 128 full.
__global__ __launch_bounds__(256, 2)
void k3a(const unsigned short* __restrict__ hnb, const float* __restrict__ src,
         const float* __restrict__ b1, const unsigned short* __restrict__ W1T,
         unsigned short* __restrict__ hid)
{
    const int tid = threadIdx.x;
    const int w = tid >> 6, l = tid & 63;
    const int lane16 = l & 15, quad = l >> 4;
    const int row0 = blockIdx.x*64 + w*16;
    f32x4 acc[8];
    for (int nt = 0; nt < 8; ++nt){
        float b = b1[nt*16 + lane16];
        f32x4 v = {b, b, b, b};
        acc[nt] = v;
    }
    const long arow = (long)(row0 + lane16);
#pragma unroll
    for (int k8 = 0; k8 < 4; ++k8){   // k in [0,128): hn (bf16)
        bf16x8 af = *reinterpret_cast<const bf16x8*>(hnb + arow*128 + 32*k8 + quad*8);
        for (int nt = 0; nt < 8; ++nt){
            int n = nt*16 + lane16;
            bf16x8 bf = *reinterpret_cast<const bf16x8*>(W1T + (long)n*256 + 32*k8 + quad*8);
            acc[nt] = __builtin_amdgcn_mfma_f32_16x16x32_bf16(af, bf, acc[nt], 0, 0, 0);
        }
    }
#pragma unroll
    for (int k8 = 0; k8 < 4; ++k8){   // k in [128,256): src (fp32 -> bf16)
        const float* pp = src + arow*128 + 32*k8 + quad*8;
        float4 lo = *reinterpret_cast<const float4*>(pp);
        float4 hi = *reinterpret_cast<const float4*>(pp + 4);
        bf16x8 af = pack8(lo, hi);
        for (int nt = 0; nt < 8; ++nt){
            int n = nt*16 + lane16;
            bf16x8 bf = *reinterpret_cast<const bf16x8*>(W1T + (long)n*256 + 128 + 32*k8 + quad*8);
            acc[nt] = __builtin_amdgcn_mfma_f32_16x16x32_bf16(af, bf, acc[nt], 0, 0, 0);
        }
    }
    for (int nt = 0; nt < 8; ++nt)
        for (int r = 0; r < 4; ++r){
            long row = row0 + quad*4 + r;
            float v = acc[nt][r];
            v = v > 0.f ? v : 0.f;
            hid[row*128 + nt*16 + lane16] = f2bf_rne(v);
        }
}

// ---------------- K3b: out = hid @ W2 + b2 (fp32 out) ----------------
__global__ __launch_bounds__(256, 2)
void k3b(const unsigned short* __restrict__ hid, const float* __restrict__ b2,
         const unsigned short* __restrict__ W2T, float* __restrict__ out)
{
    const int tid = threadIdx.x;
    const int w = tid >> 6, l = tid & 63;
    const int lane16 = l & 15, quad = l >> 4;
    const int row0 = blockIdx.x*64 + w*16;
    f32x4 acc[8];
    for (int nt = 0; nt < 8; ++nt){
        float b = b2[nt*16 + lane16];
        f32x4 v = {b, b, b, b};
        acc[nt] = v;
    }
    const long arow = (long)(row0 + lane16);
#pragma unroll
    for (int k8 = 0; k8 < 4; ++k8){
        bf16x8 af = *reinterpret_cast<const bf16x8*>(hid + arow*128 + 32*k8 + quad*8);
        for (int nt = 0; nt < 8; ++nt){
            int n = nt*16 + lane16;
            bf16x8 bf = *reinterpret_cast<const bf16x8*>(W2T + (long)n*128 + 32*k8 + quad*8);
            acc[nt] = __builtin_amdgcn_mfma_f32_16x16x32_bf16(af, bf, acc[nt], 0, 0, 0);
        }
    }
    for (int nt = 0; nt < 8; ++nt)
        for (int r = 0; r < 4; ++r){
            long row = row0 + quad*4 + r;
            out[row*128 + nt*16 + lane16] = acc[nt][r];
        }
}

extern "C" void kernel_launch(void* const* d_in, const int* in_sizes, int n_in,
                              void* d_out, int out_size, void* d_ws, size_t ws_size,
                              hipStream_t stream)
{
    (void)in_sizes; (void)n_in; (void)out_size;
    const float* src  = (const float*)d_in[0];
    // d_in[1] = src_t (unused by reference)
    const float* seq  = (const float*)d_in[2];
    const float* seqt = (const float*)d_in[3];
    const float* seqe = (const float*)d_in[4];
    // d_in[5] = mask (all ones, unused by reference)
    const float* Wi = (const float*)d_in[6];
    const float* Wh = (const float*)d_in[7];
    const float* bh = (const float*)d_in[8];
    const float* W1 = (const float*)d_in[9];
    const float* b1 = (const float*)d_in[10];
    const float* W2 = (const float*)d_in[11];
    const float* b2 = (const float*)d_in[12];
    float* out = (float*)d_out;

    // ws layout (X sized by Tc chunk of the T dimension)
    const size_t fixed = 393216 + 131072 + 65536 + 32768 + 1048576 + 1048576 + 2097152;
    int lTc = 7;
    while (lTc > 0 && fixed + (((size_t)B_ * 512 * 2) << lTc) > ws_size) --lTc;
    const int Tc = 1 << lTc;

    char* wsp = (char*)d_ws;
    size_t off = 0;
    unsigned short* X   = (unsigned short*)(wsp + off); off += ((size_t)B_ * 512 * 2) << lTc;
    unsigned short* WiT = (unsigned short*)(wsp + off); off += 393216;
    unsigned short* WhT = (unsigned short*)(wsp + off); off += 131072;
    unsigned short* W1T = (unsigned short*)(wsp + off); off += 65536;
    unsigned short* W2T = (unsigned short*)(wsp + off); off += 32768;
    unsigned short* hnb = (unsigned short*)(wsp + off); off += 1048576;
    unsigned short* hid = (unsigned short*)(wsp + off); off += 1048576;
    float* c_state      = (float*)(wsp + off);

    k0_prep<<<1216, 256, 0, stream>>>(Wi, Wh, W1, W2, WiT, WhT, W1T, W2T);
    for (int t0 = 0; t0 < T_; t0 += Tc){
        dim3 g1(4, 32 * Tc);
        k1_gemm_x<<<g1, 256, 0, stream>>>(seq, seqe, seqt, bh, WiT, X, t0, lTc);
        k2_lstm<<<256, 512, 0, stream>>>(X, WhT, hnb, c_state, t0, lTc);
    }
    k3a<<<64, 256, 0, stream>>>(hnb, src, b1, W1T, hid);
    k3b<<<64, 256, 0, stream>>>(hid, b2, W2T, out);
}